// Round 6
// baseline (184.187 us; speedup 1.0000x reference)
//
#include <hip/hip_runtime.h>
#include <math.h>

#define T_LEN 1024
#define VV 512
#define BB 64
#define NB 16
#define ANG_STEP 0.006135923151542565f   // 2*pi/1024
#define FADE_S 487
#define FADE_E 537
#define ATL 64

__device__ constexpr int KB[NB] = {1,2,3,4,5,6,7,8,12,16,24,32,48,64,96,128};

// ---------------- Kernel 0: build cos/sin table in global memory ----------------
// cst[t*32 + j] = cos(2pi*KB[j]*t/1024), cst[t*32 + 16 + j] = sin(...)
// Wave-uniform loads from this table broadcast from cache (no LDS pipe pressure).
__global__ __launch_bounds__(512) void k_cs_init(float* __restrict__ cst) {
    int i = blockIdx.x * 512 + threadIdx.x;          // i in [0, T_LEN*NB)
    int t = i >> 4, j = i & 15;
    int idx = (KB[j] * t) & (T_LEN - 1);
    float ss, cc; sincosf(ANG_STEP * (float)idx, &ss, &cc);
    cst[t * 32 + j]      = cc;
    cst[t * 32 + 16 + j] = ss;
}

// ---------------- Kernel 1: partial 16-bin DFT over a t-chunk ----------------
// grid (BB, TC), block 512, thread owns v = tid.
// Partials: xp[((b*TC + tc)*32 + q)*VV + v], q in [0,16)=re_j, [16,32)=im_j
// xi accumulates -sum(x*sin) = Im(X) for the e^{-i theta} DFT.
template<int TLEN>
__global__ __launch_bounds__(512) void k_dft_partial(const float* __restrict__ x,
                                                     const float* __restrict__ cst,
                                                     float* __restrict__ xpart,
                                                     int tc_count) {
    const int b   = blockIdx.x;
    const int tc  = blockIdx.y;
    const int tid = threadIdx.x;
    const int t0  = tc * TLEN;

    float xr[NB], xi[NB];
#pragma unroll
    for (int j = 0; j < NB; ++j) { xr[j] = 0.f; xi[j] = 0.f; }

    const float* xrd = x + ((size_t)b * T_LEN + t0) * VV + tid;
    const float* ct  = cst + (size_t)t0 * 32;

#define DFT_T(U, AV)                                        \
    do {                                                    \
        const float* cp = ct + (size_t)(t + U) * 32;        \
        _Pragma("unroll")                                   \
        for (int j = 0; j < NB; ++j) {                      \
            xr[j] = fmaf(AV, cp[j], xr[j]);                 \
            xi[j] = fmaf(-AV, cp[16 + j], xi[j]);           \
        }                                                   \
    } while (0)

    for (int t = 0; t < TLEN; t += 4) {
        float a0 = xrd[(size_t)(t + 0) * VV];
        float a1 = xrd[(size_t)(t + 1) * VV];
        float a2 = xrd[(size_t)(t + 2) * VV];
        float a3 = xrd[(size_t)(t + 3) * VV];
        DFT_T(0, a0); DFT_T(1, a1); DFT_T(2, a2); DFT_T(3, a3);
    }
#undef DFT_T

    float* o = xpart + (size_t)(b * tc_count + tc) * 32 * VV + tid;
#pragma unroll
    for (int j = 0; j < NB; ++j) {
        o[(size_t)j        * VV] = xr[j];
        o[(size_t)(NB + j) * VV] = xi[j];
    }
}

// ---------------- Kernel 2: reduce partials, apply gains -> H ----------------
// grid (BB, NB): one j-bin per block (1024 blocks).
// H layout: H[b][q][v], q: [0,16)=He_re, [16,32)=-He_im, [32,48)=Hl_re, [48,64)=-Hl_im
// (ims pre-negated: apply computes hr*cos + hi*sin = Hre*cos - Him*sin.)
__global__ __launch_bounds__(256) void k_combine(const float* __restrict__ xpart,
                                                 const float* __restrict__ ger,
                                                 const float* __restrict__ gei,
                                                 const float* __restrict__ glr,
                                                 const float* __restrict__ gli,
                                                 float* __restrict__ H, int tc_count) {
    const int b   = blockIdx.x;
    const int j   = blockIdx.y;
    const int tid = threadIdx.x;
    const int v0  = tid * 2;

    float re0 = 0.f, re1 = 0.f, im0 = 0.f, im1 = 0.f;
#pragma unroll 8
    for (int tc = 0; tc < tc_count; ++tc) {
        const float2* p = (const float2*)(xpart + (size_t)(b * tc_count + tc) * 32 * VV) + tid;
        float2 a  = p[(size_t)j        * (VV / 2)];
        float2 bb = p[(size_t)(NB + j) * (VV / 2)];
        re0 += a.x;  re1 += a.y;
        im0 += bb.x; im1 += bb.y;
    }

    const float scale = 2.0f / (float)T_LEN;
    float er0 = ger[v0 * NB + j],       ei0 = gei[v0 * NB + j];
    float lr0 = glr[v0 * NB + j],       li0 = gli[v0 * NB + j];
    float er1 = ger[(v0 + 1) * NB + j], ei1 = gei[(v0 + 1) * NB + j];
    float lr1 = glr[(v0 + 1) * NB + j], li1 = gli[(v0 + 1) * NB + j];

    float here0 = (re0 * er0 - im0 * ei0) * scale;
    float heim0 = (re0 * ei0 + im0 * er0) * scale;
    float hlre0 = (re0 * lr0 - im0 * li0) * scale;
    float hlim0 = (re0 * li0 + im0 * lr0) * scale;
    float here1 = (re1 * er1 - im1 * ei1) * scale;
    float heim1 = (re1 * ei1 + im1 * er1) * scale;
    float hlre1 = (re1 * lr1 - im1 * li1) * scale;
    float hlim1 = (re1 * li1 + im1 * lr1) * scale;

    float2* o = (float2*)(H + (size_t)b * 64 * VV) + tid;
    o[(size_t)j        * (VV / 2)] = make_float2(here0, here1);
    o[(size_t)(16 + j) * (VV / 2)] = make_float2(-heim0, -heim1);
    o[(size_t)(32 + j) * (VV / 2)] = make_float2(hlre0, hlre1);
    o[(size_t)(48 + j) * (VV / 2)] = make_float2(-hlim0, -hlim1);
}

// ---------------- Kernel 3a: pure-early/late tiles (single H set) ----------------
// grid (BB, 14), block 512, thread owns v = tid.
__global__ __launch_bounds__(512) void k_apply_pure(const float* __restrict__ x,
                                                    const float* __restrict__ cst,
                                                    const float* __restrict__ H,
                                                    float* __restrict__ out) {
    const int b    = blockIdx.x;
    const int ti   = blockIdx.y;
    const int tid  = threadIdx.x;
    const int tile = (ti < 7) ? ti : ti + 2;
    const int t0   = tile * ATL;
    const int qo   = (ti < 7) ? 0 : 32;

    float hr[NB], hi[NB];
    const float* hp = H + (size_t)b * 64 * VV + tid;
#pragma unroll
    for (int j = 0; j < NB; ++j) {
        hr[j] = hp[(size_t)(qo + j)      * VV];
        hi[j] = hp[(size_t)(qo + 16 + j) * VV];
    }

    const float* xrd = x + ((size_t)b * T_LEN + t0) * VV + tid;
    float*       ow  = out + ((size_t)b * T_LEN + t0) * VV + tid;
    const float* ct  = cst + (size_t)t0 * 32;

#define APPLY_T(U, AV)                                      \
    do {                                                    \
        const float* cp = ct + (size_t)(t + U) * 32;        \
        float s = 0.f;                                      \
        _Pragma("unroll")                                   \
        for (int j = 0; j < NB; ++j) {                      \
            s = fmaf(hr[j], cp[j], s);                      \
            s = fmaf(hi[j], cp[16 + j], s);                 \
        }                                                   \
        ow[(size_t)(t + U) * VV] = AV + s;                  \
    } while (0)

    for (int t = 0; t < ATL; t += 4) {
        float a0 = xrd[(size_t)(t + 0) * VV];
        float a1 = xrd[(size_t)(t + 1) * VV];
        float a2 = xrd[(size_t)(t + 2) * VV];
        float a3 = xrd[(size_t)(t + 3) * VV];
        APPLY_T(0, a0); APPLY_T(1, a1); APPLY_T(2, a2); APPLY_T(3, a3);
    }
#undef APPLY_T
}

// ---------------- Kernel 3b: fade tiles (both H sets) ----------------
// grid (BB, 2), block 512, thread owns v = tid.
__global__ __launch_bounds__(512) void k_apply_fade(const float* __restrict__ x,
                                                    const float* __restrict__ cst,
                                                    const float* __restrict__ H,
                                                    float* __restrict__ out) {
    const int b   = blockIdx.x;
    const int tz  = blockIdx.y;
    const int tid = threadIdx.x;
    const int t0  = (7 + tz) * ATL;

    float er[NB], ei[NB], lr[NB], li[NB];
    const float* hp = H + (size_t)b * 64 * VV + tid;
#pragma unroll
    for (int j = 0; j < NB; ++j) {
        er[j] = hp[(size_t)j        * VV];
        ei[j] = hp[(size_t)(16 + j) * VV];
        lr[j] = hp[(size_t)(32 + j) * VV];
        li[j] = hp[(size_t)(48 + j) * VV];
    }

    const float* xrd = x + ((size_t)b * T_LEN + t0) * VV + tid;
    float*       ow  = out + ((size_t)b * T_LEN + t0) * VV + tid;
    const float* ct  = cst + (size_t)t0 * 32;

    for (int t = 0; t < ATL; t += 2) {
        float a0 = xrd[(size_t)(t + 0) * VV];
        float a1 = xrd[(size_t)(t + 1) * VV];
#pragma unroll
        for (int u = 0; u < 2; ++u) {
            float av = u ? a1 : a0;
            const int tg = t0 + t + u;
            const float* cp = ct + (size_t)(t + u) * 32;
            float se = 0.f, sl = 0.f;
#pragma unroll
            for (int j = 0; j < NB; ++j) {
                float cc = cp[j], sn = cp[16 + j];
                se = fmaf(er[j], cc, se); se = fmaf(ei[j], sn, se);
                sl = fmaf(lr[j], cc, sl); sl = fmaf(li[j], sn, sl);
            }
            float w = (tg < FADE_S) ? 1.0f
                    : ((tg < FADE_E) ? (1.0f - (float)(tg - FADE_S) * (1.0f / 50.0f)) : 0.0f);
            ow[(size_t)(t + u) * VV] = av + fmaf(w, se - sl, sl);
        }
    }
}

extern "C" void kernel_launch(void* const* d_in, const int* in_sizes, int n_in,
                              void* d_out, int out_size, void* d_ws, size_t ws_size,
                              hipStream_t stream) {
    (void)in_sizes; (void)n_in; (void)out_size;
    const float* x   = (const float*)d_in[0];
    const float* ger = (const float*)d_in[1];
    const float* gei = (const float*)d_in[2];
    const float* glr = (const float*)d_in[3];
    const float* gli = (const float*)d_in[4];
    float* out = (float*)d_out;

    // ws layout: cs table (T_LEN*32 floats) | partials | H
    const size_t csflts = (size_t)T_LEN * 32;
    const size_t hflts  = (size_t)BB * 64 * VV;
    int TC;
    if ((csflts + (size_t)BB * 8 * 32 * VV + hflts) * sizeof(float) <= ws_size) TC = 8;
    else                                                                         TC = 4;

    float* cst   = (float*)d_ws;
    float* xpart = cst + csflts;
    float* H     = xpart + (size_t)BB * TC * 32 * VV;

    k_cs_init<<<dim3(T_LEN * NB / 512), 512, 0, stream>>>(cst);

    if (TC == 8) k_dft_partial<128><<<dim3(BB, 8), 512, 0, stream>>>(x, cst, xpart, 8);
    else         k_dft_partial<256><<<dim3(BB, 4), 512, 0, stream>>>(x, cst, xpart, 4);

    k_combine<<<dim3(BB, NB), 256, 0, stream>>>(xpart, ger, gei, glr, gli, H, TC);
    k_apply_pure<<<dim3(BB, 14), 512, 0, stream>>>(x, cst, H, out);
    k_apply_fade<<<dim3(BB, 2),  512, 0, stream>>>(x, cst, H, out);
}

// Round 7
// 162.335 us; speedup vs baseline: 1.1346x; 1.1346x over previous
//
#include <hip/hip_runtime.h>
#include <math.h>

#define T_LEN 1024
#define VV 512
#define VVh 256
#define BB 64
#define NB 16
#define ANG_STEP 0.006135923151542565f   // 2*pi/1024
#define FADE_S 487
#define FADE_E 537
#define ATL 64

__device__ constexpr int KB[NB] = {1,2,3,4,5,6,7,8,12,16,24,32,48,64,96,128};
// cos/sin(2*pi*k/1024) rotation-step constants (verified in R1, absmax 0.0156)
__device__ constexpr float CWT[NB] = {
    0.9999811753f, 0.9999247018f, 0.9998305818f, 0.9996988187f,
    0.9995294175f, 0.9993223846f, 0.9990777278f, 0.9987954562f,
    0.9972904567f, 0.9951847267f, 0.9891765100f, 0.9807852804f,
    0.9569403357f, 0.9238795325f, 0.8314696123f, 0.7071067812f};
__device__ constexpr float SWT[NB] = {
    0.0061358846f, 0.0122715383f, 0.0184067299f, 0.0245412285f,
    0.0306748032f, 0.0368072229f, 0.0429382569f, 0.0490676743f,
    0.0735645636f, 0.0980171403f, 0.1467304745f, 0.1950903220f,
    0.2902846773f, 0.3826834324f, 0.5555702330f, 0.7071067812f};

// ---------------- Kernel 0: cos/sin table (used by fade kernel only) ----------------
__global__ __launch_bounds__(512) void k_cs_init(float* __restrict__ cst) {
    int i = blockIdx.x * 512 + threadIdx.x;          // i in [0, T_LEN*NB)
    int t = i >> 4, j = i & 15;
    int idx = (KB[j] * t) & (T_LEN - 1);
    float ss, cc; sincosf(ANG_STEP * (float)idx, &ss, &cc);
    cst[t * 32 + j]      = cc;
    cst[t * 32 + 16 + j] = ss;
}

// ---------------- Kernel 1: partial 16-bin DFT over a t-chunk ----------------
// grid (BB, TC), block 256, thread owns v0=2*tid, v0+1 (VPT=2).
// cs generated in-register by rotation recurrence: no loads, no LDS, no latency.
// Partials: xp[((b*TC + tc)*32 + q)*VV + v], q in [0,16)=re_j, [16,32)=im_j
template<int TLEN>
__global__ __launch_bounds__(256, 2) void k_dft_partial(const float* __restrict__ x,
                                                        float* __restrict__ xpart,
                                                        int tc_count) {
    const int b   = blockIdx.x;
    const int tc  = blockIdx.y;
    const int tid = threadIdx.x;
    const int t0  = tc * TLEN;

    float xr0[NB], xi0[NB], xr1[NB], xi1[NB], c[NB], s[NB];
#pragma unroll
    for (int j = 0; j < NB; ++j) {
        xr0[j] = xi0[j] = xr1[j] = xi1[j] = 0.0f;
        int n0 = (KB[j] * t0) & (T_LEN - 1);
        sincosf(ANG_STEP * (float)n0, &s[j], &c[j]);
    }

    const float2* xrd = (const float2*)(x + ((size_t)b * T_LEN + t0) * VV) + tid;

#define DFT_STEP(AV)                                            \
    do {                                                        \
        _Pragma("unroll")                                       \
        for (int j = 0; j < NB; ++j) {                          \
            xr0[j] = fmaf(AV.x, c[j], xr0[j]);                  \
            xi0[j] = fmaf(-AV.x, s[j], xi0[j]);                 \
            xr1[j] = fmaf(AV.y, c[j], xr1[j]);                  \
            xi1[j] = fmaf(-AV.y, s[j], xi1[j]);                 \
            float cn = fmaf(c[j], CWT[j], -(s[j] * SWT[j]));    \
            float sn = fmaf(s[j], CWT[j], c[j] * SWT[j]);       \
            c[j] = cn; s[j] = sn;                               \
        }                                                       \
    } while (0)

    // software-pipelined: group i+1 loads issued before group i compute
    float2 a0 = xrd[(size_t)0 * VVh];
    float2 a1 = xrd[(size_t)1 * VVh];
    float2 a2 = xrd[(size_t)2 * VVh];
    float2 a3 = xrd[(size_t)3 * VVh];
#pragma unroll 1
    for (int t = 0; t < TLEN - 4; t += 4) {
        float2 b0 = xrd[(size_t)(t + 4) * VVh];
        float2 b1 = xrd[(size_t)(t + 5) * VVh];
        float2 b2 = xrd[(size_t)(t + 6) * VVh];
        float2 b3 = xrd[(size_t)(t + 7) * VVh];
        DFT_STEP(a0); DFT_STEP(a1); DFT_STEP(a2); DFT_STEP(a3);
        a0 = b0; a1 = b1; a2 = b2; a3 = b3;
    }
    DFT_STEP(a0); DFT_STEP(a1); DFT_STEP(a2); DFT_STEP(a3);
#undef DFT_STEP

    float2* o = (float2*)(xpart + (size_t)(b * tc_count + tc) * 32 * VV) + tid;
#pragma unroll
    for (int j = 0; j < NB; ++j) {
        o[(size_t)j        * VVh] = make_float2(xr0[j], xr1[j]);
        o[(size_t)(NB + j) * VVh] = make_float2(xi0[j], xi1[j]);
    }
}

// ---------------- Kernel 2: reduce partials, apply gains -> H ----------------
// grid (BB, NB): one j-bin per block (1024 blocks).
// H layout: H[b][q][v], q: [0,16)=He_re, [16,32)=-He_im, [32,48)=Hl_re, [48,64)=-Hl_im
// (ims pre-negated: apply computes hr*cos + hi*sin = Hre*cos - Him*sin.)
__global__ __launch_bounds__(256) void k_combine(const float* __restrict__ xpart,
                                                 const float* __restrict__ ger,
                                                 const float* __restrict__ gei,
                                                 const float* __restrict__ glr,
                                                 const float* __restrict__ gli,
                                                 float* __restrict__ H, int tc_count) {
    const int b   = blockIdx.x;
    const int j   = blockIdx.y;
    const int tid = threadIdx.x;
    const int v0  = tid * 2;

    float re0 = 0.f, re1 = 0.f, im0 = 0.f, im1 = 0.f;
#pragma unroll 8
    for (int tc = 0; tc < tc_count; ++tc) {
        const float2* p = (const float2*)(xpart + (size_t)(b * tc_count + tc) * 32 * VV) + tid;
        float2 a  = p[(size_t)j        * VVh];
        float2 bb = p[(size_t)(NB + j) * VVh];
        re0 += a.x;  re1 += a.y;
        im0 += bb.x; im1 += bb.y;
    }

    const float scale = 2.0f / (float)T_LEN;
    float er0 = ger[v0 * NB + j],       ei0 = gei[v0 * NB + j];
    float lr0 = glr[v0 * NB + j],       li0 = gli[v0 * NB + j];
    float er1 = ger[(v0 + 1) * NB + j], ei1 = gei[(v0 + 1) * NB + j];
    float lr1 = glr[(v0 + 1) * NB + j], li1 = gli[(v0 + 1) * NB + j];

    float here0 = (re0 * er0 - im0 * ei0) * scale;
    float heim0 = (re0 * ei0 + im0 * er0) * scale;
    float hlre0 = (re0 * lr0 - im0 * li0) * scale;
    float hlim0 = (re0 * li0 + im0 * lr0) * scale;
    float here1 = (re1 * er1 - im1 * ei1) * scale;
    float heim1 = (re1 * ei1 + im1 * er1) * scale;
    float hlre1 = (re1 * lr1 - im1 * li1) * scale;
    float hlim1 = (re1 * li1 + im1 * lr1) * scale;

    float2* o = (float2*)(H + (size_t)b * 64 * VV) + tid;
    o[(size_t)j        * VVh] = make_float2(here0, here1);
    o[(size_t)(16 + j) * VVh] = make_float2(-heim0, -heim1);
    o[(size_t)(32 + j) * VVh] = make_float2(hlre0, hlre1);
    o[(size_t)(48 + j) * VVh] = make_float2(-hlim0, -hlim1);
}

// ---------------- Kernel 3a: pure-early/late tiles (single H set) ----------------
// grid (BB, 14), block 256, thread owns v0=2*tid, v0+1. Recurrence cs, prefetched x.
__global__ __launch_bounds__(256, 2) void k_apply_pure(const float* __restrict__ x,
                                                       const float* __restrict__ H,
                                                       float* __restrict__ out) {
    const int b    = blockIdx.x;
    const int ti   = blockIdx.y;
    const int tid  = threadIdx.x;
    const int tile = (ti < 7) ? ti : ti + 2;
    const int t0   = tile * ATL;
    const int qo   = (ti < 7) ? 0 : 32;

    float hr0[NB], hi0[NB], hr1[NB], hi1[NB], c[NB], s[NB];
    const float2* hp = (const float2*)(H + (size_t)b * 64 * VV) + tid;
#pragma unroll
    for (int j = 0; j < NB; ++j) {
        float2 a  = hp[(size_t)(qo + j)      * VVh]; hr0[j] = a.x;  hr1[j] = a.y;
        float2 bq = hp[(size_t)(qo + 16 + j) * VVh]; hi0[j] = bq.x; hi1[j] = bq.y;
        int n0 = (KB[j] * t0) & (T_LEN - 1);
        sincosf(ANG_STEP * (float)n0, &s[j], &c[j]);
    }

    const float2* xrd = (const float2*)(x + ((size_t)b * T_LEN + t0) * VV) + tid;
    float2*       ow  = (float2*)(out + ((size_t)b * T_LEN + t0) * VV) + tid;

#define APPLY_STEP(U, AV)                                       \
    do {                                                        \
        float s0 = 0.f, s1 = 0.f;                               \
        _Pragma("unroll")                                       \
        for (int j = 0; j < NB; ++j) {                          \
            s0 = fmaf(hr0[j], c[j], s0);                        \
            s0 = fmaf(hi0[j], s[j], s0);                        \
            s1 = fmaf(hr1[j], c[j], s1);                        \
            s1 = fmaf(hi1[j], s[j], s1);                        \
            float cn = fmaf(c[j], CWT[j], -(s[j] * SWT[j]));    \
            float sn = fmaf(s[j], CWT[j], c[j] * SWT[j]);       \
            c[j] = cn; s[j] = sn;                               \
        }                                                       \
        ow[(size_t)(t + U) * VVh] =                             \
            make_float2(AV.x + s0, AV.y + s1);                  \
    } while (0)

    float2 a0 = xrd[(size_t)0 * VVh];
    float2 a1 = xrd[(size_t)1 * VVh];
    float2 a2 = xrd[(size_t)2 * VVh];
    float2 a3 = xrd[(size_t)3 * VVh];
#pragma unroll 1
    for (int t = 0; t < ATL - 4; t += 4) {
        float2 b0 = xrd[(size_t)(t + 4) * VVh];
        float2 b1 = xrd[(size_t)(t + 5) * VVh];
        float2 b2 = xrd[(size_t)(t + 6) * VVh];
        float2 b3 = xrd[(size_t)(t + 7) * VVh];
        APPLY_STEP(0, a0); APPLY_STEP(1, a1); APPLY_STEP(2, a2); APPLY_STEP(3, a3);
        a0 = b0; a1 = b1; a2 = b2; a3 = b3;
    }
    {
        const int t = ATL - 4;
        APPLY_STEP(0, a0); APPLY_STEP(1, a1); APPLY_STEP(2, a2); APPLY_STEP(3, a3);
    }
#undef APPLY_STEP
}

// ---------------- Kernel 3b: fade tiles (both H sets), cst-table path ----------------
// grid (BB, 2), block 512, thread owns v = tid. Only 2/16 tiles; not critical.
__global__ __launch_bounds__(512) void k_apply_fade(const float* __restrict__ x,
                                                    const float* __restrict__ cst,
                                                    const float* __restrict__ H,
                                                    float* __restrict__ out) {
    const int b   = blockIdx.x;
    const int tz  = blockIdx.y;
    const int tid = threadIdx.x;
    const int t0  = (7 + tz) * ATL;

    float er[NB], ei[NB], lr[NB], li[NB];
    const float* hp = H + (size_t)b * 64 * VV + tid;
#pragma unroll
    for (int j = 0; j < NB; ++j) {
        er[j] = hp[(size_t)j        * VV];
        ei[j] = hp[(size_t)(16 + j) * VV];
        lr[j] = hp[(size_t)(32 + j) * VV];
        li[j] = hp[(size_t)(48 + j) * VV];
    }

    const float* xrd = x + ((size_t)b * T_LEN + t0) * VV + tid;
    float*       ow  = out + ((size_t)b * T_LEN + t0) * VV + tid;
    const float* ct  = cst + (size_t)t0 * 32;

    for (int t = 0; t < ATL; t += 2) {
        float a0 = xrd[(size_t)(t + 0) * VV];
        float a1 = xrd[(size_t)(t + 1) * VV];
#pragma unroll
        for (int u = 0; u < 2; ++u) {
            float av = u ? a1 : a0;
            const int tg = t0 + t + u;
            const float* cp = ct + (size_t)(t + u) * 32;
            float se = 0.f, sl = 0.f;
#pragma unroll
            for (int j = 0; j < NB; ++j) {
                float cc = cp[j], sn = cp[16 + j];
                se = fmaf(er[j], cc, se); se = fmaf(ei[j], sn, se);
                sl = fmaf(lr[j], cc, sl); sl = fmaf(li[j], sn, sl);
            }
            float w = (tg < FADE_S) ? 1.0f
                    : ((tg < FADE_E) ? (1.0f - (float)(tg - FADE_S) * (1.0f / 50.0f)) : 0.0f);
            ow[(size_t)(t + u) * VV] = av + fmaf(w, se - sl, sl);
        }
    }
}

extern "C" void kernel_launch(void* const* d_in, const int* in_sizes, int n_in,
                              void* d_out, int out_size, void* d_ws, size_t ws_size,
                              hipStream_t stream) {
    (void)in_sizes; (void)n_in; (void)out_size;
    const float* x   = (const float*)d_in[0];
    const float* ger = (const float*)d_in[1];
    const float* gei = (const float*)d_in[2];
    const float* glr = (const float*)d_in[3];
    const float* gli = (const float*)d_in[4];
    float* out = (float*)d_out;

    // ws layout: cs table (T_LEN*32 floats) | partials | H
    const size_t csflts = (size_t)T_LEN * 32;
    const size_t hflts  = (size_t)BB * 64 * VV;
    int TC;
    if ((csflts + (size_t)BB * 8 * 32 * VV + hflts) * sizeof(float) <= ws_size) TC = 8;
    else                                                                         TC = 4;

    float* cst   = (float*)d_ws;
    float* xpart = cst + csflts;
    float* H     = xpart + (size_t)BB * TC * 32 * VV;

    k_cs_init<<<dim3(T_LEN * NB / 512), 512, 0, stream>>>(cst);

    if (TC == 8) k_dft_partial<128><<<dim3(BB, 8), 256, 0, stream>>>(x, xpart, 8);
    else         k_dft_partial<256><<<dim3(BB, 4), 256, 0, stream>>>(x, xpart, 4);

    k_combine<<<dim3(BB, NB), 256, 0, stream>>>(xpart, ger, gei, glr, gli, H, TC);
    k_apply_pure<<<dim3(BB, 14), 256, 0, stream>>>(x, H, out);
    k_apply_fade<<<dim3(BB, 2),  512, 0, stream>>>(x, cst, H, out);
}